// Round 7
// baseline (1158.546 us; speedup 1.0000x reference)
//
#include <hip/hip_runtime.h>

// DMPNN encoder, MI355X bf16-MFMA, round 13: ws-safe retry of fused segsum1.
//
// Round-12 crashed; audit found no kernel-level bug -> primary theory is
// workspace overflow (245.2 -> 273.8 MB; tail allocations past ws_size).
// Round-13: (1) alias one 25.6MB region X across time {CSR temps} ->
// {f32 tmpF} -> {bf16 tmp}; (2) drop oe[] (epilogue gathers sidx[stA.*] a
// full iteration ahead; oe[p]=sidx[pidx[p]]); (3) runtime guard on ws_size
// picks fused (253.95MB) vs round-11 unfused (241MB) path; (4) k_init LDS =
// single 20-slot stride-80 tile, slots 0..15 XOR-swizzled (proven 2-way),
// kc4 tail plain (minor conflict, off critical path), no bk4 reg bank.
//
// Pipeline identities: fidx[p]=rev[eidx[p]], sidx[p]=dst[eidx[p]] (sorted),
// pidx[p]=posOf[fidx[p]] involution, node(tile row p) = sidx[pidx[p]] for
// ALL three accumulations (k_init/k_msg1 -> seq segsum over written row
// pidx[p] resp. f-row p; k_msg2 -> gather segsum at i=pidx[p]).
//
// Weight channel permutation c(p) = (p&64) + 2*(p&15) + ((p>>4)&1) + 32*((p>>5)&1):
// lane ln's j-pair (2a,2a+1) holds channels 32a+2ln, 32a+2ln+1 -> packed u32
// stores; u32 col u holds channels 2u,2u+1 (natural order).

typedef unsigned int u32;
typedef unsigned short u16;
using bf16x8 = __attribute__((ext_vector_type(8))) __bf16;
using f32x4  = __attribute__((ext_vector_type(4))) float;

#define NN 50000
#define NP 400000
#define NE 800000
#define AF 133
#define HID 128
#define ATU 68      // atomBf row stride in u32
#define KPU1 80     // Wi packed row stride in u32 (160 cols = 5 kc chunks)
#define WHU 64      // Wh packed row stride (u32) = 256 B rows
#define KPU3 148    // k_out stride; 144 data u32 = 288 cols = 9 chunks
#define KC3 9
#define NCH 196     // scan chunks of 256 covering NN

__device__ __forceinline__ u16 f2bf(float f) {
    union { float f; u32 u; } x; x.f = f;
    u32 r = x.u + 0x7fffu + ((x.u >> 16) & 1u);   // RNE
    return (u16)(r >> 16);
}
__device__ __forceinline__ float bf2f(u16 b) {
    union { u32 u; float f; } x; x.u = ((u32)b) << 16;
    return x.f;
}
__device__ __forceinline__ float lo16(u32 v) { return bf2f((u16)v); }
__device__ __forceinline__ float hi16(u32 v) { return bf2f((u16)(v >> 16)); }
__device__ __forceinline__ u32 pack2(float a, float b) {
    return (u32)f2bf(a) | ((u32)f2bf(b) << 16);
}
__device__ __forceinline__ float relu(float v) { return v > 0.f ? v : 0.f; }

// single-instruction RNE pack of two f32 -> packed bf16x2 (no builtin on gfx950)
__device__ __forceinline__ u32 cvt_pk_bf16(float lo, float hi) {
    u32 r;
    asm("v_cvt_pk_bf16_f32 %0, %1, %2" : "=v"(r) : "v"(lo), "v"(hi));
    return r;
}
__device__ __forceinline__ float bfLO(u32 v) {
    union { u32 u; float f; } x; x.u = v << 16; return x.f;
}
__device__ __forceinline__ float bfHI(u32 v) {
    union { u32 u; float f; } x; x.u = v & 0xffff0000u; return x.f;
}
__device__ __forceinline__ u32 sub2_pk(u32 t, u32 h) {
    return cvt_pk_bf16(bfLO(t) - bfLO(h), bfHI(t) - bfHI(h));
}
__device__ __forceinline__ u32 relu2_pk(float a, float b) {
    return cvt_pk_bf16(a > 0.f ? a : 0.f, b > 0.f ? b : 0.f);
}

union frag_cast { uint4 u; bf16x8 v; };

// ---------------- precompute kernels ----------------

__global__ void cvt_atom(const float* __restrict__ atom, u32* __restrict__ out) {
    int total = NN * ATU;
    for (int i = blockIdx.x * blockDim.x + threadIdx.x; i < total; i += gridDim.x * blockDim.x) {
        int n = i / ATU;
        int cu = i - n * ATU;
        int k = 2 * cu;
        float f0 = (k < AF) ? atom[n * AF + k] : 0.f;
        float f1 = (k + 1 < AF) ? atom[n * AF + k + 1] : 0.f;
        out[i] = pack2(f0, f1);
    }
}

__device__ __forceinline__ float wcol(const float* W, int n, int Kw, int len1, int off2, int len2, int k) {
    if (k < len1) return W[n * Kw + k];
    int j = k - off2;
    if (j >= 0 && j < len2) return W[n * Kw + len1 + j];
    return 0.f;
}
__global__ void cvt_w(const float* __restrict__ W, u32* __restrict__ out,
                      int Kw, int KpU, int len1, int off2, int len2) {
    int total = 128 * KpU;
    for (int i = blockIdx.x * blockDim.x + threadIdx.x; i < total; i += gridDim.x * blockDim.x) {
        int p = i / KpU;
        int cu = i - p * KpU;
        int t = p & 63;
        int c = (p & 64) + 2 * (t & 15) + ((t >> 4) & 1) + 32 * ((t >> 5) & 1);
        int k = 2 * cu;
        out[i] = pack2(wcol(W, c, Kw, len1, off2, len2, k),
                       wcol(W, c, Kw, len1, off2, len2, k + 1));
    }
}

// ---------------- CSR build ----------------

__global__ void hist(const int* __restrict__ dst, int* __restrict__ cnt) {
    for (int e = blockIdx.x * blockDim.x + threadIdx.x; e < NE; e += gridDim.x * blockDim.x)
        atomicAdd(&cnt[dst[e]], 1);
}

__global__ void scan1(const int* __restrict__ cnt, int* __restrict__ lexc, int* __restrict__ chunkSum) {
    __shared__ int s[256];
    int t = threadIdx.x, idx = blockIdx.x * 256 + t;
    int v = (idx < NN) ? cnt[idx] : 0;
    s[t] = v; __syncthreads();
    for (int off = 1; off < 256; off <<= 1) {
        int x = (t >= off) ? s[t - off] : 0;
        __syncthreads();
        s[t] += x;
        __syncthreads();
    }
    if (idx < NN) lexc[idx] = s[t] - v;
    if (t == 255) chunkSum[blockIdx.x] = s[255];
}

__global__ void scan2(const int* __restrict__ chunkSum, int* __restrict__ chunkOff) {
    __shared__ int s[256];
    int t = threadIdx.x;
    int v = (t < NCH) ? chunkSum[t] : 0;
    s[t] = v; __syncthreads();
    for (int off = 1; off < 256; off <<= 1) {
        int x = (t >= off) ? s[t - off] : 0;
        __syncthreads();
        s[t] += x;
        __syncthreads();
    }
    if (t < NCH) chunkOff[t] = s[t] - v;
}

__global__ void scan3(const int* __restrict__ lexc, const int* __restrict__ chunkOff,
                      int* __restrict__ rowptr, int* __restrict__ cursor) {
    int idx = blockIdx.x * 256 + threadIdx.x;
    if (idx < NN) {
        int v = lexc[idx] + chunkOff[blockIdx.x];
        rowptr[idx] = v;
        cursor[idx] = v;
    }
    if (idx == 0) rowptr[NN] = NE;
}

__global__ void scatter(const int* __restrict__ dst, const int* __restrict__ rev,
                        int* __restrict__ cursor, int* __restrict__ fidx,
                        int* __restrict__ sidx, int* __restrict__ posOf) {
    for (int e = blockIdx.x * blockDim.x + threadIdx.x; e < NE; e += gridDim.x * blockDim.x) {
        int d = dst[e];
        int pos = atomicAdd(&cursor[d], 1);
        fidx[pos] = rev[e];
        sidx[pos] = d;        // = src[fidx[pos]], nondecreasing over pos
        posOf[e] = pos;
    }
}

__global__ void pidx_build(const int* __restrict__ fidx, const int* __restrict__ posOf,
                           int* __restrict__ pidx) {
    for (int p = blockIdx.x * blockDim.x + threadIdx.x; p < NE; p += gridDim.x * blockDim.x)
        pidx[p] = posOf[fidx[p]];
}

// ---------------- segment sum ----------------
template<bool G>
__global__ __launch_bounds__(256)
void segsum_t(const int* __restrict__ rowptr, const int* __restrict__ gat,
              const u32* __restrict__ h, u32* __restrict__ tmp) {
    const int lane = threadIdx.x & 63;
    const int wv = threadIdx.x >> 6;
    const int rsel = lane >> 4;
    const int cg = lane & 15;
    const int nwaves = gridDim.x * 4;
    for (int n = blockIdx.x * 4 + wv; n < NN; n += nwaves) {
        int beg = rowptr[n], end = rowptr[n + 1];
        float a0 = 0, a1 = 0, a2 = 0, a3 = 0, a4 = 0, a5 = 0, a6 = 0, a7 = 0;
        int i = beg;
        for (; i + 8 <= end; i += 8) {
            int rA = G ? gat[i + rsel] : (i + rsel);
            int rB = G ? gat[i + 4 + rsel] : (i + 4 + rsel);
            uint4 hA = *(const uint4*)(h + (size_t)rA * 64 + 4 * cg);
            uint4 hB = *(const uint4*)(h + (size_t)rB * 64 + 4 * cg);
            a0 += lo16(hA.x) + lo16(hB.x); a1 += hi16(hA.x) + hi16(hB.x);
            a2 += lo16(hA.y) + lo16(hB.y); a3 += hi16(hA.y) + hi16(hB.y);
            a4 += lo16(hA.z) + lo16(hB.z); a5 += hi16(hA.z) + hi16(hB.z);
            a6 += lo16(hA.w) + lo16(hB.w); a7 += hi16(hA.w) + hi16(hB.w);
        }
        for (; i < end; i += 4) {
            if (i + rsel < end) {
                int rA = G ? gat[i + rsel] : (i + rsel);
                uint4 hA = *(const uint4*)(h + (size_t)rA * 64 + 4 * cg);
                a0 += lo16(hA.x); a1 += hi16(hA.x);
                a2 += lo16(hA.y); a3 += hi16(hA.y);
                a4 += lo16(hA.z); a5 += hi16(hA.z);
                a6 += lo16(hA.w); a7 += hi16(hA.w);
            }
        }
        a0 += __shfl_xor(a0, 16); a0 += __shfl_xor(a0, 32);
        a1 += __shfl_xor(a1, 16); a1 += __shfl_xor(a1, 32);
        a2 += __shfl_xor(a2, 16); a2 += __shfl_xor(a2, 32);
        a3 += __shfl_xor(a3, 16); a3 += __shfl_xor(a3, 32);
        a4 += __shfl_xor(a4, 16); a4 += __shfl_xor(a4, 32);
        a5 += __shfl_xor(a5, 16); a5 += __shfl_xor(a5, 32);
        a6 += __shfl_xor(a6, 16); a6 += __shfl_xor(a6, 32);
        a7 += __shfl_xor(a7, 16); a7 += __shfl_xor(a7, 32);
        if (rsel == 0) {
            uint4 o;
            o.x = pack2(a0, a1); o.y = pack2(a2, a3);
            o.z = pack2(a4, a5); o.w = pack2(a6, a7);
            *(uint4*)(tmp + (size_t)n * 64 + 4 * cg) = o;
        }
    }
}

// ---------------- k_init: persistent waves, VMEM-free MFMA loop ----------------
// A row p = concat(atomBf[sidx[p]] (136 cols), bondBf[fidx[p]] (14 cols), pad).
// Wi in one LDS tile: 20 slots/row, stride 80 u32 (40960 B -> 4 blocks/CU);
// slots 0..15 XOR-swizzled (proven 2-way free), 16..19 plain. FUSE: epilogue
// also atomicAdds relu'd f32 into tmpF[node], node = sidx[pidx-quad] gathered
// one iteration ahead (wave-uniform per q-group -> broadcast loads).
template<bool FUSE>
__global__ __launch_bounds__(256, 4)
void k_init_t(const u32* __restrict__ atomBf, const float* __restrict__ bond,
              const int* __restrict__ fidx, const int* __restrict__ sidx,
              const int* __restrict__ pidx, const u32* __restrict__ Wp,
              u32* __restrict__ hout, float* __restrict__ tmpF)
{
    __shared__ u32 Wlds[128 * 80];   // 40960 B -> 4 blocks/CU
    const int tid  = threadIdx.x;
    const int lane = tid & 63;
    const int wv   = tid >> 6;
    const int ln   = lane & 15;
    const int q    = lane >> 4;

    {
        const int row = tid >> 1;        // 128 rows, 2 threads/row
        const int half = tid & 1;        // 10 slots of 16 B each
        const int rx = row & 15;
        #pragma unroll
        for (int sl = 0; sl < 10; ++sl) {
            int L = half * 10 + sl;      // 0..19
            int P = (L < 16) ? (L ^ rx) : L;
            *(uint4*)(Wlds + row * 80 + P * 4) = *(const uint4*)(Wp + row * KPU1 + L * 4);
        }
    }
    __syncthreads();

    const int NT = NE / 16;              // 50000 tiles of 16 rows
    const int stride = gridDim.x * 4;
    int s = blockIdx.x * 4 + wv;
    if (s >= NT) return;

    uint4  rA[4];                        // kc0..3 fragment raw (atom, already bf16)
    uint4  rA4;                          // q==0: atom u32 64..67
    float2 b01, b23, b45, b67;           // q==1: bond f0..7 ; q==2: f8..13
    int4   stA, oeA;                     // store-row quad + accumulation-node quad

    // ---- prologue: gathers for the first tile
    {
        int p = s * 16 + ln;
        int sr = sidx[p];
        int fr = fidx[p];
        stA = *(const int4*)(pidx + s * 16 + 4 * q);
        if constexpr (FUSE) {
            oeA.x = sidx[stA.x]; oeA.y = sidx[stA.y];
            oeA.z = sidx[stA.z]; oeA.w = sidx[stA.w];
        }
        const u32* ab = atomBf + (size_t)sr * ATU;
        #pragma unroll
        for (int kc = 0; kc < 4; ++kc)
            rA[kc] = *(const uint4*)(ab + kc * 16 + q * 4);
        if (q == 0) rA4 = *(const uint4*)(ab + 64);
        const float* bp = bond + (size_t)fr * 14;
        if (q == 1) {
            b01 = *(const float2*)(bp + 0); b23 = *(const float2*)(bp + 2);
            b45 = *(const float2*)(bp + 4); b67 = *(const float2*)(bp + 6);
        } else if (q == 2) {
            b01 = *(const float2*)(bp + 8); b23 = *(const float2*)(bp + 10);
            b45 = *(const float2*)(bp + 12);
        }
    }

    while (true) {
        const int sn = s + stride;
        const bool more = sn < NT;       // wave-uniform

        int srB = 0, frB = 0;
        int4 stB, oeB;
        if (more) {
            int p = sn * 16 + ln;
            srB = sidx[p];
            frB = fidx[p];
            stB = *(const int4*)(pidx + sn * 16 + 4 * q);
        }

        // build A fragments (consumes raw regs; kc0-3 are pure bitcasts)
        bf16x8 aF[5];
        #pragma unroll
        for (int kc = 0; kc < 4; ++kc) { frag_cast fc; fc.u = rA[kc]; aF[kc] = fc.v; }
        {
            frag_cast f4;
            if (q == 0)      f4.u = rA4;
            else if (q == 1) f4.u = make_uint4(cvt_pk_bf16(b01.x, b01.y), cvt_pk_bf16(b23.x, b23.y),
                                               cvt_pk_bf16(b45.x, b45.y), cvt_pk_bf16(b67.x, b67.y));
            else if (q == 2) f4.u = make_uint4(cvt_pk_bf16(b01.x, b01.y), cvt_pk_bf16(b23.x, b23.y),
                                               cvt_pk_bf16(b45.x, b45.y), 0u);
            else             f4.u = make_uint4(0u, 0u, 0u, 0u);
            aF[4] = f4.v;
        }

        // prefetch next tile's gathers (stay in flight across MFMA + stores)
        if (more) {
            if constexpr (FUSE) {
                oeB.x = sidx[stB.x]; oeB.y = sidx[stB.y];
                oeB.z = sidx[stB.z]; oeB.w = sidx[stB.w];
            }
            const u32* ab = atomBf + (size_t)srB * ATU;
            #pragma unroll
            for (int kc = 0; kc < 4; ++kc)
                rA[kc] = *(const uint4*)(ab + kc * 16 + q * 4);
            if (q == 0) rA4 = *(const uint4*)(ab + 64);
            const float* bp = bond + (size_t)frB * 14;
            if (q == 1) {
                b01 = *(const float2*)(bp + 0); b23 = *(const float2*)(bp + 2);
                b45 = *(const float2*)(bp + 4); b67 = *(const float2*)(bp + 6);
            } else if (q == 2) {
                b01 = *(const float2*)(bp + 8); b23 = *(const float2*)(bp + 10);
                b45 = *(const float2*)(bp + 12);
            }
        }

        // MFMA 16x128, K=160; B from LDS only.
        u32 zoff = 0;
        asm volatile("" : "+v"(zoff));   // defeat LICM: keep B ds_reads in-loop
        f32x4 acc[8] = {};
        #pragma unroll
        for (int kc = 0; kc < 5; ++kc) {
            const int P = (kc < 4) ? ((kc * 4 + q) ^ ln) : (16 + q);
            const u32* wrow = Wlds + zoff + ln * 80 + P * 4;
            #pragma unroll
            for (int j = 0; j < 8; ++j) {
                bf16x8 b = *(const bf16x8*)(wrow + j * 1280);   // +16 rows * 80 u32
                acc[j] = __builtin_amdgcn_mfma_f32_16x16x32_bf16(aF[kc], b, acc[j], 0, 0, 0);
            }
        }

        // epilogue: full 256-B rows to hout[pidx] (+ fused segsum1 atomics)
        #pragma unroll
        for (int r = 0; r < 4; ++r) {
            int wrow = (r == 0) ? stA.x : (r == 1) ? stA.y : (r == 2) ? stA.z : stA.w;
            u32* orow = hout + (size_t)wrow * 64;
            if constexpr (FUSE) {
                int node = (r == 0) ? oeA.x : (r == 1) ? oeA.y : (r == 2) ? oeA.z : oeA.w;
                float* trow = tmpF + (size_t)node * 128 + 2 * ln;
                #pragma unroll
                for (int a = 0; a < 4; ++a) {
                    float v0 = relu(acc[2 * a][r]);
                    float v1 = relu(acc[2 * a + 1][r]);
                    orow[16 * a + ln] = cvt_pk_bf16(v0, v1);
                    atomicAdd(trow + 32 * a, v0);
                    atomicAdd(trow + 32 * a + 1, v1);
                }
            } else {
                #pragma unroll
                for (int a = 0; a < 4; ++a)
                    orow[16 * a + ln] = relu2_pk(acc[2 * a][r], acc[2 * a + 1][r]);
            }
        }

        if (!more) break;
        s = sn;
        stA = stB;
        if constexpr (FUSE) oeA = oeB;
    }
}

// ---------------- k_msg: persistent waves, VMEM-free MFMA loop ----------------
// Row p: msg = tmp[sidx[p]] - h[hr], hr = USEIDX ? pidx[p] : p; written back
// to row hr. TF32: tmp operand is the f32 atomic-accumulated buffer.
template<bool USEIDX, bool TF32>
__global__ __launch_bounds__(256, 4)
void k_msg_t(const int* __restrict__ sidx, const int* __restrict__ pidx,
             const u32* __restrict__ Wp, const void* __restrict__ tmpv,
             u32* __restrict__ h)
{
    const u32*   tmpu = (const u32*)tmpv;
    const float* tmpf = (const float*)tmpv;
    __shared__ u32 Wlds[128 * 64];   // 32 KB; slot phys = slot ^ (row&15)
    const int tid  = threadIdx.x;
    const int lane = tid & 63;
    const int wv   = tid >> 6;
    const int ln   = lane & 15;
    const int q    = lane >> 4;

    {
        const int row = tid >> 1;        // 128 rows, 2 threads/row
        const int half = tid & 1;        // 8 slots of 16 B each
        const int rx = row & 15;
        #pragma unroll
        for (int sl = 0; sl < 8; ++sl) {
            int L = half * 8 + sl;
            int P = L ^ rx;
            *(uint4*)(Wlds + row * 64 + P * 4) = *(const uint4*)(Wp + row * 64 + L * 4);
        }
    }
    __syncthreads();

    const int NT = NE / 16;              // 50000 tiles of 16 rows
    const int stride = gridDim.x * 4;
    int s = blockIdx.x * 4 + wv;
    if (s >= NT) return;

    int4   stA;                          // store-row quad (USEIDX only)
    uint4  tv[4], hv[4];                 // raw gathered operands (bf16 tmp path)
    float4 ta[4], tb[4];                 // raw gathered operands (f32 tmp path)

    // ---- prologue: gathers for the first tile
    {
        int p = s * 16 + ln;
        int sr = sidx[p];
        int hr = USEIDX ? pidx[p] : p;
        if (USEIDX) stA = *(const int4*)(pidx + s * 16 + 4 * q);
        const u32* hb = h + (size_t)hr * 64 + q * 4;
        #pragma unroll
        for (int kc = 0; kc < 4; ++kc)
            hv[kc] = *(const uint4*)(hb + kc * 16);
        if constexpr (TF32) {
            const float* tb0 = tmpf + (size_t)sr * 128 + q * 8;
            #pragma unroll
            for (int kc = 0; kc < 4; ++kc) {
                ta[kc] = *(const float4*)(tb0 + kc * 32);
                tb[kc] = *(const float4*)(tb0 + kc * 32 + 4);
            }
        } else {
            const u32* tb0 = tmpu + (size_t)sr * 64 + q * 4;
            #pragma unroll
            for (int kc = 0; kc < 4; ++kc)
                tv[kc] = *(const uint4*)(tb0 + kc * 16);
        }
    }

    while (true) {
        const int sn = s + stride;
        const bool more = sn < NT;       // wave-uniform

        int srB = 0, hrB = 0;
        int4 stB;
        if (more) {
            int p = sn * 16 + ln;
            srB = sidx[p];
            hrB = USEIDX ? pidx[p] : p;
            if (USEIDX) stB = *(const int4*)(pidx + sn * 16 + 4 * q);
        }

        // convert current raw -> A fragments (frees raw regs)
        bf16x8 aF[4];
        #pragma unroll
        for (int kc = 0; kc < 4; ++kc) {
            frag_cast fc;
            if constexpr (TF32) {
                fc.u.x = cvt_pk_bf16(ta[kc].x - bfLO(hv[kc].x), ta[kc].y - bfHI(hv[kc].x));
                fc.u.y = cvt_pk_bf16(ta[kc].z - bfLO(hv[kc].y), ta[kc].w - bfHI(hv[kc].y));
                fc.u.z = cvt_pk_bf16(tb[kc].x - bfLO(hv[kc].z), tb[kc].y - bfHI(hv[kc].z));
                fc.u.w = cvt_pk_bf16(tb[kc].z - bfLO(hv[kc].w), tb[kc].w - bfHI(hv[kc].w));
            } else {
                fc.u.x = sub2_pk(tv[kc].x, hv[kc].x);
                fc.u.y = sub2_pk(tv[kc].y, hv[kc].y);
                fc.u.z = sub2_pk(tv[kc].z, hv[kc].z);
                fc.u.w = sub2_pk(tv[kc].w, hv[kc].w);
            }
            aF[kc] = fc.v;
        }

        // prefetch next tile's gathers (stay in flight across MFMA + stores)
        if (more) {
            const u32* hb = h + (size_t)hrB * 64 + q * 4;
            #pragma unroll
            for (int kc = 0; kc < 4; ++kc)
                hv[kc] = *(const uint4*)(hb + kc * 16);
            if constexpr (TF32) {
                const float* tb0 = tmpf + (size_t)srB * 128 + q * 8;
                #pragma unroll
                for (int kc = 0; kc < 4; ++kc) {
                    ta[kc] = *(const float4*)(tb0 + kc * 32);
                    tb[kc] = *(const float4*)(tb0 + kc * 32 + 4);
                }
            } else {
                const u32* tb0 = tmpu + (size_t)srB * 64 + q * 4;
                #pragma unroll
                for (int kc = 0; kc < 4; ++kc)
                    tv[kc] = *(const uint4*)(tb0 + kc * 16);
            }
        }

        // MFMA 16x128, K=128; B from LDS only.
        u32 zoff = 0;
        asm volatile("" : "+v"(zoff));   // defeat LICM: keep B ds_reads in-loop
        f32x4 acc[8] = {};
        #pragma unroll
        for (int kc = 0; kc < 4; ++kc) {
            const u32* wrow = Wlds + zoff + ln * 64 + (((kc * 4 + q) ^ ln) << 2);
            #pragma unroll
            for (int j = 0; j < 8; ++j) {
                bf16x8 b = *(const bf16x8*)(wrow + j * 1024);
                acc[j] = __builtin_amdgcn_mfma_f32_16x16x32_bf16(aF[kc], b, acc[j], 0, 0, 0);
            }
        }

        // epilogue: full 256-B rows, 4 consecutive 64-B segment stores per row
        #pragma unroll
        for (int r = 0; r < 4; ++r) {
            int wrow = USEIDX
                ? ((r == 0) ? stA.x : (r == 1) ? stA.y : (r == 2) ? stA.z : stA.w)
                : (s * 16 + 4 * q + r);
            u32* orow = h + (size_t)wrow * 64;
            #pragma unroll
            for (int a = 0; a < 4; ++a)
                orow[16 * a + ln] = relu2_pk(acc[2 * a][r], acc[2 * a + 1][r]);
        }

        if (!more) break;
        s = sn;
        if (USEIDX) stA = stB;
    }
}

// ---------------- k_out: 64-node tiles, 4 waves (32x64 each) ----------------
__global__ __launch_bounds__(256, 4)
void k_out(const u32* __restrict__ atomBf, const u32* __restrict__ Wp,
           const u32* __restrict__ tmp, float* __restrict__ out)
{
    __shared__ u32 As[64 * KPU3];   // 37888 B -> 4 blocks/CU
    const int tid = threadIdx.x;
    const int lane = tid & 63;
    const int wv = tid >> 6;
    const int ln = lane & 15;
    const int q  = lane >> 4;
    const int rowBase = 32 * (wv >> 1);
    const int colBase = 64 * (wv & 1);
    const int ntiles = (NN + 63) / 64;

    const int srow = tid >> 2;
    const int qt = tid & 3;
    const uint4 z4 = make_uint4(0u, 0u, 0u, 0u);

    for (int tile = blockIdx.x; tile < ntiles; tile += gridDim.x) {
        const int n0 = tile * 64;
        {
            int n = n0 + srow;
            bool ok = n < NN;
            const u32* ap = atomBf + (size_t)n * ATU;
            const u32* tp = tmp + (size_t)n * 64;
            u32* dr = As + srow * KPU3;
            if (qt == 0) {
                #pragma unroll
                for (int j = 0; j < 9; ++j)
                    *(uint4*)(dr + 4 * j) = ok ? *(const uint4*)(ap + 4 * j) : z4;
            } else if (qt == 1) {
                #pragma unroll
                for (int j = 9; j < 17; ++j)
                    *(uint4*)(dr + 4 * j) = ok ? *(const uint4*)(ap + 4 * j) : z4;
            } else if (qt == 2) {
                #pragma unroll
                for (int j = 0; j < 8; ++j)
                    *(uint4*)(dr + 68 + 4 * j) = ok ? *(const uint4*)(tp + 4 * j) : z4;
                *(uint4*)(dr + 132) = z4;
            } else {
                #pragma unroll
                for (int j = 8; j < 16; ++j)
                    *(uint4*)(dr + 68 + 4 * j) = ok ? *(const uint4*)(tp + 4 * j) : z4;
                *(uint4*)(dr + 136) = z4;
                *(uint4*)(dr + 140) = z4;
            }
        }
        __syncthreads();

        f32x4 acc[2][4] = {};
        #pragma unroll
        for (int kc = 0; kc < KC3; ++kc) {
            const int kHalf = kc * 16 + q * 4;
            bf16x8 a[2], b[4];
            #pragma unroll
            for (int i = 0; i < 2; ++i)
                a[i] = *(const bf16x8*)(&As[(rowBase + 16 * i + ln) * KPU3 + kHalf]);
            #pragma unroll
            for (int j = 0; j < 4; ++j)
                b[j] = *(const bf16x8*)(Wp + (colBase + 16 * j + ln) * KPU3 + kHalf);
            #pragma unroll
            for (int i = 0; i < 2; ++i)
                #pragma unroll
                for (int j = 0; j < 4; ++j)
                    acc[i][j] = __builtin_amdgcn_mfma_f32_16x16x32_bf16(a[i], b[j], acc[i][j], 0, 0, 0);
        }
        __syncthreads();

        #pragma unroll
        for (int i = 0; i < 2; ++i) {
            #pragma unroll
            for (int r = 0; r < 4; ++r) {
                int n = n0 + rowBase + 16 * i + q * 4 + r;
                if (n < NN) {
                    float2* orow = (float2*)(out + (size_t)n * HID);
                    float2 v01, v23;
                    v01.x = relu(acc[i][0][r]); v01.y = relu(acc[i][1][r]);
                    v23.x = relu(acc[i][2][r]); v23.y = relu(acc[i][3][r]);
                    orow[(colBase >> 1) + ln]      = v01;
                    orow[(colBase >> 1) + 16 + ln] = v23;
                }
            }
        }
    }
}

// ---------------- launch ----------------

extern "C" void kernel_launch(void* const* d_in, const int* in_sizes, int n_in,
                              void* d_out, int out_size, void* d_ws, size_t ws_size,
                              hipStream_t stream) {
    const float* atom = (const float*)d_in[0];   // [50000][133]
    const float* bond = (const float*)d_in[1];   // [800000][14]
    const float* Wi   = (const float*)d_in[2];   // [128][147]
    const float* Wh   = (const float*)d_in[3];   // [128][128]
    const float* Wo   = (const float*)d_in[4];   // [128][261]
    const int*   src  = (const int*)d_in[5]; (void)src;
    const int*   dst  = (const int*)d_in[6];
    const int*   rev  = (const int*)d_in[7];
    float* out = (float*)d_out;

    char* ws = (char*)d_ws;
    size_t off = 0;
    auto take = [&](size_t bytes) { char* p = ws + off; off = (off + bytes + 255) & ~(size_t)255; return p; };
    // persistent buffers first (X last, so unfused path touches less)
    u32* hbuf   = (u32*)take((size_t)NE * 64 * 4);     // 204.8 MB
    u32* atomBf = (u32*)take((size_t)NN * ATU * 4);    // 13.6 MB
    int* fidx   = (int*)take((size_t)NE * 4);
    int* sidx   = (int*)take((size_t)NE * 4);
    int* pidx   = (int*)take((size_t)NE * 4);
    int* rowptr = (int*)take((size_t)(NN + 1) * 4);
    u32* WiP = (u32*)take(128 * KPU1 * 4);
    u32* WhP = (u32*)take(128 * WHU * 4);
    u32* WoP = (u32*)take(128 * KPU3 * 4);
    char* X  = take((size_t)NN * 128 * 4);             // 25.6 MB, time-shared
    const size_t totalFused = off;                     // ~254.0 MB
    // aliases inside X (disjoint in time):
    //   phase CSR-build: posOf, cnt, lexc, cursor, chunkSum, chunkOff
    //   phase k_init/k_msg1 (fused): tmpF (f32, whole X)
    //   phase segsum2..k_out: tmp (bf16, first 12.8 MB)
    int* posOf    = (int*)(X);
    int* cnt      = (int*)(X + 3200000);
    int* lexc     = (int*)(X + 3400192);
    int* cursor   = (int*)(X + 3600384);
    int* chunkSum = (int*)(X + 3800576);
    int* chunkOff = (int*)(X + 3801856);
    float* tmpF   = (float*)X;
    u32*   tmp    = (u32*)X;

    const bool fused = (totalFused <= ws_size);

    cvt_atom<<<2048, 256, 0, stream>>>(atom, atomBf);
    cvt_w<<<48, 256, 0, stream>>>(Wi, WiP, 147, KPU1, 133, 136, 14);
    cvt_w<<<32, 256, 0, stream>>>(Wh, WhP, 128, WHU, 128, 1 << 20, 0);
    cvt_w<<<80, 256, 0, stream>>>(Wo, WoP, 261, KPU3, 133, 136, 128);

    hipMemsetAsync(cnt, 0, (size_t)NN * 4, stream);
    hist<<<1024, 256, 0, stream>>>(dst, cnt);
    scan1<<<NCH, 256, 0, stream>>>(cnt, lexc, chunkSum);
    scan2<<<1, 256, 0, stream>>>(chunkSum, chunkOff);
    scan3<<<NCH, 256, 0, stream>>>(lexc, chunkOff, rowptr, cursor);
    scatter<<<1024, 256, 0, stream>>>(dst, rev, cursor, fidx, sidx, posOf);
    pidx_build<<<1024, 256, 0, stream>>>(fidx, posOf, pidx);

    if (fused) {
        // CSR temps in X are dead now; zero X for the f32 atomic accumulator
        hipMemsetAsync(X, 0, (size_t)NN * 128 * 4, stream);
        k_init_t<true><<<1024, 256, 0, stream>>>(atomBf, bond, fidx, sidx, pidx, WiP, hbuf, tmpF);
        k_msg_t<false, true><<<1024, 256, 0, stream>>>(sidx, pidx, WhP, tmpF, hbuf);
    } else {
        k_init_t<false><<<1024, 256, 0, stream>>>(atomBf, bond, fidx, sidx, pidx, WiP, hbuf, tmpF);
        segsum_t<false><<<2048, 256, 0, stream>>>(rowptr, nullptr, hbuf, tmp);
        k_msg_t<false, false><<<1024, 256, 0, stream>>>(sidx, pidx, WhP, tmp, hbuf);
    }
    segsum_t<true><<<2048, 256, 0, stream>>>(rowptr, pidx, hbuf, tmp);            // gather
    k_msg_t<true, false><<<1024, 256, 0, stream>>>(sidx, pidx, WhP, tmp, hbuf);   // random rows -> e-layout
    segsum_t<false><<<2048, 256, 0, stream>>>(rowptr, nullptr, hbuf, tmp);        // sequential
    k_out<<<782, 256, 0, stream>>>(atomBf, WoP, tmp, out);
}

// Round 8
// 572.661 us; speedup vs baseline: 2.0231x; 2.0231x over previous
//
#include <hip/hip_runtime.h>

// DMPNN encoder, MI355X bf16-MFMA, round 14: revert atomic fusion (r13: 102M
// device-scope atomics -> 1.0 GB WRITE, 663us; cross-XCD L2 line ping-pong)
// + persistent-pipeline k_out.
//
// Pipeline (pos-space, alternating e-/f-layout; identities:
//   fidx[p]=rev[eidx[p]], sidx[p]=dst[eidx[p]] (sorted),
//   pidx[p]=posOf[fidx[p]] fix-point-free involution):
//   k_init : persistent waves, Wi in LDS (96-stride 24-slot XOR), e-layout @pidx[p]
//   segsum1: sequential (e-layout)
//   k_msg1 : tmp[sidx[p]] - h0@p -> h1 f-layout @p      (all-stream)
//   segsum2: gather rows pidx[seg]
//   k_msg2 : tmp[sidx[p]] - h1@pidx[p] -> h2 e-layout @pidx[p]
//   segsum3: sequential
//   k_out  : NEW persistent 16-node tiles; A from global (atomBf+tmp, 9 uint4
//            slices, q-conditional), Wo in LDS stride 148 u32 (148%32=20 ->
//            16 lanes hit 8 distinct 4-bank spans x2 = conflict-free, no
//            swizzle), 1-deep prefetch, full 512-B f32 row stores.
//
// Weight channel permutation c(p) = (p&64) + 2*(p&15) + ((p>>4)&1) + 32*((p>>5)&1):
// acc pair (2a,2a+1) at lane ln = channels 32a+2ln, 32a+2ln+1 (verified in
// k_msg); f32 out -> float2 store at index 16a+ln.

typedef unsigned int u32;
typedef unsigned short u16;
using bf16x8 = __attribute__((ext_vector_type(8))) __bf16;
using f32x4  = __attribute__((ext_vector_type(4))) float;

#define NN 50000
#define NP 400000
#define NE 800000
#define AF 133
#define HID 128
#define ATU 68      // atomBf row stride in u32
#define KPU1 80     // Wi packed row stride in u32 (160 cols = 5 kc chunks)
#define WHU 64      // Wh packed row stride (u32) = 256 B rows
#define KPU3 148    // Wo packed row stride; 144 data u32 = 288 cols = 9 chunks
#define KC3 9
#define NCH 196     // scan chunks of 256 covering NN

__device__ __forceinline__ u16 f2bf(float f) {
    union { float f; u32 u; } x; x.f = f;
    u32 r = x.u + 0x7fffu + ((x.u >> 16) & 1u);   // RNE
    return (u16)(r >> 16);
}
__device__ __forceinline__ float bf2f(u16 b) {
    union { u32 u; float f; } x; x.u = ((u32)b) << 16;
    return x.f;
}
__device__ __forceinline__ float lo16(u32 v) { return bf2f((u16)v); }
__device__ __forceinline__ float hi16(u32 v) { return bf2f((u16)(v >> 16)); }
__device__ __forceinline__ u32 pack2(float a, float b) {
    return (u32)f2bf(a) | ((u32)f2bf(b) << 16);
}
__device__ __forceinline__ float relu(float v) { return v > 0.f ? v : 0.f; }

// single-instruction RNE pack of two f32 -> packed bf16x2 (no builtin on gfx950)
__device__ __forceinline__ u32 cvt_pk_bf16(float lo, float hi) {
    u32 r;
    asm("v_cvt_pk_bf16_f32 %0, %1, %2" : "=v"(r) : "v"(lo), "v"(hi));
    return r;
}
__device__ __forceinline__ float bfLO(u32 v) {
    union { u32 u; float f; } x; x.u = v << 16; return x.f;
}
__device__ __forceinline__ float bfHI(u32 v) {
    union { u32 u; float f; } x; x.u = v & 0xffff0000u; return x.f;
}
__device__ __forceinline__ u32 sub2_pk(u32 t, u32 h) {
    return cvt_pk_bf16(bfLO(t) - bfLO(h), bfHI(t) - bfHI(h));
}
__device__ __forceinline__ u32 relu2_pk(float a, float b) {
    return cvt_pk_bf16(a > 0.f ? a : 0.f, b > 0.f ? b : 0.f);
}

union frag_cast { uint4 u; bf16x8 v; };

// ---------------- precompute kernels ----------------

__global__ void cvt_atom(const float* __restrict__ atom, u32* __restrict__ out) {
    int total = NN * ATU;
    for (int i = blockIdx.x * blockDim.x + threadIdx.x; i < total; i += gridDim.x * blockDim.x) {
        int n = i / ATU;
        int cu = i - n * ATU;
        int k = 2 * cu;
        float f0 = (k < AF) ? atom[n * AF + k] : 0.f;
        float f1 = (k + 1 < AF) ? atom[n * AF + k + 1] : 0.f;
        out[i] = pack2(f0, f1);
    }
}

__device__ __forceinline__ float wcol(const float* W, int n, int Kw, int len1, int off2, int len2, int k) {
    if (k < len1) return W[n * Kw + k];
    int j = k - off2;
    if (j >= 0 && j < len2) return W[n * Kw + len1 + j];
    return 0.f;
}
__global__ void cvt_w(const float* __restrict__ W, u32* __restrict__ out,
                      int Kw, int KpU, int len1, int off2, int len2) {
    int total = 128 * KpU;
    for (int i = blockIdx.x * blockDim.x + threadIdx.x; i < total; i += gridDim.x * blockDim.x) {
        int p = i / KpU;
        int cu = i - p * KpU;
        int t = p & 63;
        int c = (p & 64) + 2 * (t & 15) + ((t >> 4) & 1) + 32 * ((t >> 5) & 1);
        int k = 2 * cu;
        out[i] = pack2(wcol(W, c, Kw, len1, off2, len2, k),
                       wcol(W, c, Kw, len1, off2, len2, k + 1));
    }
}

// ---------------- CSR build ----------------

__global__ void hist(const int* __restrict__ dst, int* __restrict__ cnt) {
    for (int e = blockIdx.x * blockDim.x + threadIdx.x; e < NE; e += gridDim.x * blockDim.x)
        atomicAdd(&cnt[dst[e]], 1);
}

__global__ void scan1(const int* __restrict__ cnt, int* __restrict__ lexc, int* __restrict__ chunkSum) {
    __shared__ int s[256];
    int t = threadIdx.x, idx = blockIdx.x * 256 + t;
    int v = (idx < NN) ? cnt[idx] : 0;
    s[t] = v; __syncthreads();
    for (int off = 1; off < 256; off <<= 1) {
        int x = (t >= off) ? s[t - off] : 0;
        __syncthreads();
        s[t] += x;
        __syncthreads();
    }
    if (idx < NN) lexc[idx] = s[t] - v;
    if (t == 255) chunkSum[blockIdx.x] = s[255];
}

__global__ void scan2(const int* __restrict__ chunkSum, int* __restrict__ chunkOff) {
    __shared__ int s[256];
    int t = threadIdx.x;
    int v = (t < NCH) ? chunkSum[t] : 0;
    s[t] = v; __syncthreads();
    for (int off = 1; off < 256; off <<= 1) {
        int x = (t >= off) ? s[t - off] : 0;
        __syncthreads();
        s[t] += x;
        __syncthreads();
    }
    if (t < NCH) chunkOff[t] = s[t] - v;
}

__global__ void scan3(const int* __restrict__ lexc, const int* __restrict__ chunkOff,
                      int* __restrict__ rowptr, int* __restrict__ cursor) {
    int idx = blockIdx.x * 256 + threadIdx.x;
    if (idx < NN) {
        int v = lexc[idx] + chunkOff[blockIdx.x];
        rowptr[idx] = v;
        cursor[idx] = v;
    }
    if (idx == 0) rowptr[NN] = NE;
}

__global__ void scatter(const int* __restrict__ dst, const int* __restrict__ rev,
                        int* __restrict__ cursor, int* __restrict__ fidx,
                        int* __restrict__ sidx, int* __restrict__ posOf) {
    for (int e = blockIdx.x * blockDim.x + threadIdx.x; e < NE; e += gridDim.x * blockDim.x) {
        int d = dst[e];
        int pos = atomicAdd(&cursor[d], 1);
        fidx[pos] = rev[e];
        sidx[pos] = d;        // = src[fidx[pos]], nondecreasing over pos
        posOf[e] = pos;
    }
}

__global__ void pidx_build(const int* __restrict__ fidx, const int* __restrict__ posOf,
                           int* __restrict__ pidx) {
    for (int p = blockIdx.x * blockDim.x + threadIdx.x; p < NE; p += gridDim.x * blockDim.x)
        pidx[p] = posOf[fidx[p]];
}

// ---------------- segment sum ----------------
template<bool G>
__global__ __launch_bounds__(256)
void segsum_t(const int* __restrict__ rowptr, const int* __restrict__ gat,
              const u32* __restrict__ h, u32* __restrict__ tmp) {
    const int lane = threadIdx.x & 63;
    const int wv = threadIdx.x >> 6;
    const int rsel = lane >> 4;
    const int cg = lane & 15;
    const int nwaves = gridDim.x * 4;
    for (int n = blockIdx.x * 4 + wv; n < NN; n += nwaves) {
        int beg = rowptr[n], end = rowptr[n + 1];
        float a0 = 0, a1 = 0, a2 = 0, a3 = 0, a4 = 0, a5 = 0, a6 = 0, a7 = 0;
        int i = beg;
        for (; i + 8 <= end; i += 8) {
            int rA = G ? gat[i + rsel] : (i + rsel);
            int rB = G ? gat[i + 4 + rsel] : (i + 4 + rsel);
            uint4 hA = *(const uint4*)(h + (size_t)rA * 64 + 4 * cg);
            uint4 hB = *(const uint4*)(h + (size_t)rB * 64 + 4 * cg);
            a0 += lo16(hA.x) + lo16(hB.x); a1 += hi16(hA.x) + hi16(hB.x);
            a2 += lo16(hA.y) + lo16(hB.y); a3 += hi16(hA.y) + hi16(hB.y);
            a4 += lo16(hA.z) + lo16(hB.z); a5 += hi16(hA.z) + hi16(hB.z);
            a6 += lo16(hA.w) + lo16(hB.w); a7 += hi16(hA.w) + hi16(hB.w);
        }
        for (; i < end; i += 4) {
            if (i + rsel < end) {
                int rA = G ? gat[i + rsel] : (i + rsel);
                uint4 hA = *(const uint4*)(h + (size_t)rA * 64 + 4 * cg);
                a0 += lo16(hA.x); a1 += hi16(hA.x);
                a2 += lo16(hA.y); a3 += hi16(hA.y);
                a4 += lo16(hA.z); a5 += hi16(hA.z);
                a6 += lo16(hA.w); a7 += hi16(hA.w);
            }
        }
        a0 += __shfl_xor(a0, 16); a0 += __shfl_xor(a0, 32);
        a1 += __shfl_xor(a1, 16); a1 += __shfl_xor(a1, 32);
        a2 += __shfl_xor(a2, 16); a2 += __shfl_xor(a2, 32);
        a3 += __shfl_xor(a3, 16); a3 += __shfl_xor(a3, 32);
        a4 += __shfl_xor(a4, 16); a4 += __shfl_xor(a4, 32);
        a5 += __shfl_xor(a5, 16); a5 += __shfl_xor(a5, 32);
        a6 += __shfl_xor(a6, 16); a6 += __shfl_xor(a6, 32);
        a7 += __shfl_xor(a7, 16); a7 += __shfl_xor(a7, 32);
        if (rsel == 0) {
            uint4 o;
            o.x = pack2(a0, a1); o.y = pack2(a2, a3);
            o.z = pack2(a4, a5); o.w = pack2(a6, a7);
            *(uint4*)(tmp + (size_t)n * 64 + 4 * cg) = o;
        }
    }
}

// ---------------- k_init: persistent waves, VMEM-free MFMA loop ----------------
// (round-9 proven form: stride-96 LDS, 24-slot XOR with rx=row&7, 3 blocks/CU)
__global__ __launch_bounds__(256, 3)
void k_init(const u32* __restrict__ atomBf, const float* __restrict__ bond,
            const int* __restrict__ fidx, const int* __restrict__ sidx,
            const int* __restrict__ pidx, const u32* __restrict__ Wp,
            u32* __restrict__ hout)
{
    __shared__ u32 Wlds[128 * 96];   // 49152 B; phys slot = slot ^ (row&7)
    const int tid  = threadIdx.x;
    const int lane = tid & 63;
    const int wv   = tid >> 6;
    const int ln   = lane & 15;
    const int q    = lane >> 4;

    {
        const int row = tid >> 1;        // 128 rows, 2 threads/row
        const int half = tid & 1;        // 10 slots of 16 B each
        const int rx = row & 7;
        #pragma unroll
        for (int sl = 0; sl < 10; ++sl) {
            int L = half * 10 + sl;      // 0..19
            int P = L ^ rx;              // <= 23, fits 24-slot stride
            *(uint4*)(Wlds + row * 96 + P * 4) = *(const uint4*)(Wp + row * KPU1 + L * 4);
        }
    }
    __syncthreads();

    const int NT = NE / 16;              // 50000 tiles of 16 rows
    const int stride = gridDim.x * 4;
    int s = blockIdx.x * 4 + wv;
    if (s >= NT) return;

    uint4  rA[4];
    uint4  rA4;
    float2 b01, b23, b45, b67;
    int4   stA;

    {
        int p = s * 16 + ln;
        int sr = sidx[p];
        int fr = fidx[p];
        stA = *(const int4*)(pidx + s * 16 + 4 * q);
        const u32* ab = atomBf + (size_t)sr * ATU;
        #pragma unroll
        for (int kc = 0; kc < 4; ++kc)
            rA[kc] = *(const uint4*)(ab + kc * 16 + q * 4);
        if (q == 0) rA4 = *(const uint4*)(ab + 64);
        const float* bp = bond + (size_t)fr * 14;
        if (q == 1) {
            b01 = *(const float2*)(bp + 0); b23 = *(const float2*)(bp + 2);
            b45 = *(const float2*)(bp + 4); b67 = *(const float2*)(bp + 6);
        } else if (q == 2) {
            b01 = *(const float2*)(bp + 8); b23 = *(const float2*)(bp + 10);
            b45 = *(const float2*)(bp + 12);
        }
    }

    while (true) {
        const int sn = s + stride;
        const bool more = sn < NT;       // wave-uniform

        int srB = 0, frB = 0;
        int4 stB;
        if (more) {
            int p = sn * 16 + ln;
            srB = sidx[p];
            frB = fidx[p];
            stB = *(const int4*)(pidx + sn * 16 + 4 * q);
        }

        bf16x8 aF[5];
        #pragma unroll
        for (int kc = 0; kc < 4; ++kc) { frag_cast fc; fc.u = rA[kc]; aF[kc] = fc.v; }
        {
            frag_cast f4;
            if (q == 0)      f4.u = rA4;
            else if (q == 1) f4.u = make_uint4(cvt_pk_bf16(b01.x, b01.y), cvt_pk_bf16(b23.x, b23.y),
                                               cvt_pk_bf16(b45.x, b45.y), cvt_pk_bf16(b67.x, b67.y));
            else if (q == 2) f4.u = make_uint4(cvt_pk_bf16(b01.x, b01.y), cvt_pk_bf16(b23.x, b23.y),
                                               cvt_pk_bf16(b45.x, b45.y), 0u);
            else             f4.u = make_uint4(0u, 0u, 0u, 0u);
            aF[4] = f4.v;
        }

        if (more) {
            const u32* ab = atomBf + (size_t)srB * ATU;
            #pragma unroll
            for (int kc = 0; kc < 4; ++kc)
                rA[kc] = *(const uint4*)(ab + kc * 16 + q * 4);
            if (q == 0) rA4 = *(const uint4*)(ab + 64);
            const float* bp = bond + (size_t)frB * 14;
            if (q == 1) {
                b01 = *(const float2*)(bp + 0); b23 = *(const float2*)(bp + 2);
                b45 = *(const float2*)(bp + 4); b67 = *(const float2*)(bp + 6);
            } else if (q == 2) {
                b01 = *(const float2*)(bp + 8); b23 = *(const float2*)(bp + 10);
                b45 = *(const float2*)(bp + 12);
            }
        }

        u32 zoff = 0;
        asm volatile("" : "+v"(zoff));   // defeat LICM: keep B ds_reads in-loop
        f32x4 acc[8] = {};
        #pragma unroll
        for (int kc = 0; kc < 5; ++kc) {
            const u32* wrow = Wlds + zoff + ln * 96 + (((kc * 4 + q) ^ (ln & 7)) << 2);
            #pragma unroll
            for (int j = 0; j < 8; ++j) {
                bf16x8 b = *(const bf16x8*)(wrow + j * 1536);   // +16 rows * 96 u32
                acc[j] = __builtin_amdgcn_mfma_f32_16x16x32_bf16(aF[kc], b, acc[j], 0, 0, 0);
            }
        }

        #pragma unroll
        for (int r = 0; r < 4; ++r) {
            int wrow = (r == 0) ? stA.x : (r == 1) ? stA.y : (r == 2) ? stA.z : stA.w;
            u32* orow = hout + (size_t)wrow * 64;
            #pragma unroll
            for (int a = 0; a < 4; ++a)
                orow[16 * a + ln] = relu2_pk(acc[2 * a][r], acc[2 * a + 1][r]);
        }

        if (!more) break;
        s = sn;
        stA = stB;
    }
}

// ---------------- k_msg: persistent waves, VMEM-free MFMA loop ----------------
template<bool USEIDX>
__global__ __launch_bounds__(256, 4)
void k_msg_t(const int* __restrict__ sidx, const int* __restrict__ pidx,
             const u32* __restrict__ Wp, const u32* __restrict__ tmp,
             u32* __restrict__ h)
{
    __shared__ u32 Wlds[128 * 64];   // 32 KB; slot phys = slot ^ (row&15)
    const int tid  = threadIdx.x;
    const int lane = tid & 63;
    const int wv   = tid >> 6;
    const int ln   = lane & 15;
    const int q    = lane >> 4;

    {
        const int row = tid >> 1;        // 128 rows, 2 threads/row
        const int half = tid & 1;        // 8 slots of 16 B each
        const int rx = row & 15;
        #pragma unroll
        for (int sl = 0; sl < 8; ++sl) {
            int L = half * 8 + sl;
            int P = L ^ rx;
            *(uint4*)(Wlds + row * 64 + P * 4) = *(const uint4*)(Wp + row * 64 + L * 4);
        }
    }
    __syncthreads();

    const int NT = NE / 16;              // 50000 tiles of 16 rows
    const int stride = gridDim.x * 4;
    int s = blockIdx.x * 4 + wv;
    if (s >= NT) return;

    int4  stA;
    uint4 tv[4], hv[4];

    {
        int p = s * 16 + ln;
        int sr = sidx[p];
        int hr = USEIDX ? pidx[p] : p;
        if (USEIDX) stA = *(const int4*)(pidx + s * 16 + 4 * q);
        const u32* tb = tmp + (size_t)sr * 64 + q * 4;
        const u32* hb = h   + (size_t)hr * 64 + q * 4;
        #pragma unroll
        for (int kc = 0; kc < 4; ++kc) {
            tv[kc] = *(const uint4*)(tb + kc * 16);
            hv[kc] = *(const uint4*)(hb + kc * 16);
        }
    }

    while (true) {
        const int sn = s + stride;
        const bool more = sn < NT;       // wave-uniform

        int srB = 0, hrB = 0;
        int4 stB;
        if (more) {
            int p = sn * 16 + ln;
            srB = sidx[p];
            hrB = USEIDX ? pidx[p] : p;
            if (USEIDX) stB = *(const int4*)(pidx + sn * 16 + 4 * q);
        }

        bf16x8 aF[4];
        #pragma unroll
        for (int kc = 0; kc < 4; ++kc) {
            frag_cast fc;
            fc.u.x = sub2_pk(tv[kc].x, hv[kc].x);
            fc.u.y = sub2_pk(tv[kc].y, hv[kc].y);
            fc.u.z = sub2_pk(tv[kc].z, hv[kc].z);
            fc.u.w = sub2_pk(tv[kc].w, hv[kc].w);
            aF[kc] = fc.v;
        }

        if (more) {
            const u32* tb = tmp + (size_t)srB * 64 + q * 4;
            const u32* hb = h   + (size_t)hrB * 64 + q * 4;
            #pragma unroll
            for (int kc = 0; kc < 4; ++kc) {
                tv[kc] = *(const uint4*)(tb + kc * 16);
                hv[kc] = *(const uint4*)(hb + kc * 16);
            }
        }

        u32 zoff = 0;
        asm volatile("" : "+v"(zoff));   // defeat LICM: keep B ds_reads in-loop
        f32x4 acc[8] = {};
        #pragma unroll
        for (int kc = 0; kc < 4; ++kc) {
            const u32* wrow = Wlds + zoff + ln * 64 + (((kc * 4 + q) ^ ln) << 2);
            #pragma unroll
            for (int j = 0; j < 8; ++j) {
                bf16x8 b = *(const bf16x8*)(wrow + j * 1024);
                acc[j] = __builtin_amdgcn_mfma_f32_16x16x32_bf16(aF[kc], b, acc[j], 0, 0, 0);
            }
        }

        #pragma unroll
        for (int r = 0; r < 4; ++r) {
            int wrow = USEIDX
                ? ((r == 0) ? stA.x : (r == 1) ? stA.y : (r == 2) ? stA.z : stA.w)
                : (s * 16 + 4 * q + r);
            u32* orow = h + (size_t)wrow * 64;
            #pragma unroll
            for (int a = 0; a < 4; ++a)
                orow[16 * a + ln] = relu2_pk(acc[2 * a][r], acc[2 * a + 1][r]);
        }

        if (!more) break;
        s = sn;
        if (USEIDX) stA = stB;
    }
}

// ---------------- k_out: persistent 16-node tiles, VMEM-free MFMA loop ----------------
// A row n = concat(atom 136 cols [atomBf u32 0..67], tmp 128 cols [tmp u32
// 0..63], pad). Per-lane uint4 slices: kc0-3 atom; kc4 q0=atom 64..67 /
// q1-3=tmp (q-1)*4; kc5-7 tmp 12/28/44+4q; kc8 q0=tmp 60..63, else 0.
// Wo in LDS stride 148 u32: 148%32=20 -> 16 lanes spread over 8 distinct
// 4-bank spans x2 lanes = conflict-free without swizzle.
__global__ __launch_bounds__(256, 2)
void k_out_p(const u32* __restrict__ atomBf, const u32* __restrict__ Wp,
             const u32* __restrict__ tmp, float* __restrict__ out)
{
    __shared__ u32 Wlds[128 * KPU3];   // 75776 B -> 2 blocks/CU
    const int tid  = threadIdx.x;
    const int lane = tid & 63;
    const int wv   = tid >> 6;
    const int ln   = lane & 15;
    const int q    = lane >> 4;

    {
        const int row = tid >> 1;        // 128 rows, 2 threads/row
        const int half = tid & 1;        // 18 slots of 16 B each
        #pragma unroll
        for (int sl = 0; sl < 18; ++sl) {
            int L = half * 18 + sl;      // 0..35
            *(uint4*)(Wlds + row * KPU3 + L * 4) = *(const uint4*)(Wp + row * KPU3 + L * 4);
        }
    }
    __syncthreads();

    const int NT = NN / 16;              // 3125 tiles of 16 nodes
    const int stride = gridDim.x * 4;
    int s = blockIdx.x * 4 + wv;
    if (s >= NT) return;

    uint4 rA[9];
    // gather tile ss's A slices for this lane
    auto gather = [&](int ss, uint4* r) {
        int n = ss * 16 + ln;
        const u32* ab = atomBf + (size_t)n * ATU;
        const u32* tp = tmp + (size_t)n * 64;
        #pragma unroll
        for (int kc = 0; kc < 4; ++kc)
            r[kc] = *(const uint4*)(ab + kc * 16 + q * 4);
        if (q == 0) {
            r[4] = *(const uint4*)(ab + 64);
            r[5] = *(const uint4*)(tp + 12);
            r[6] = *(const uint4*)(tp + 28);
            r[7] = *(const uint4*)(tp + 44);
            r[8] = *(const uint4*)(tp + 60);
        } else {
            r[4] = *(const uint4*)(tp + (q - 1) * 4);
            r[5] = *(const uint4*)(tp + 12 + q * 4);
            r[6] = *(const uint4*)(tp + 28 + q * 4);
            r[7] = *(const uint4*)(tp + 44 + q * 4);
            r[8] = make_uint4(0u, 0u, 0u, 0u);
        }
    };

    gather(s, rA);

    while (true) {
        const int sn = s + stride;
        const bool more = sn < NT;       // wave-uniform

        bf16x8 aF[9];
        #pragma unroll
        for (int kc = 0; kc < 9; ++kc) { frag_cast fc; fc.u = rA[kc]; aF[kc] = fc.v; }

        if (more) gather(sn, rA);        // prefetch rides through MFMA (LDS B)

        u32 zoff = 0;
        asm volatile("" : "+v"(zoff));   // defeat LICM: keep B ds_reads in-loop
        f32x4 acc[8] = {};
        #pragma unroll
        for (int kc = 0; kc < KC3; ++kc) {
            const u32* wrow = Wlds + zoff + ln * KPU3 + (kc * 4 + q) * 4;
            #pragma unroll
            for (int j = 0; j < 8; ++j) {
                bf16x8 b = *(const bf16x8*)(wrow + j * (16 * KPU3));
                acc[j] = __builtin_amdgcn_mfma_f32_16x16x32_bf16(aF[kc], b, acc[j], 0, 0, 0);
            }
        }

        // store: 16 nodes x 128 f32; channel(a, ln) = 32a + 2ln (+1)
        #pragma unroll
        for (int r = 0; r < 4; ++r) {
            int n = s * 16 + 4 * q + r;
            float2* orow = (float2*)(out + (size_t)n * HID);
            #pragma unroll
            for (int a = 0; a < 4; ++a) {
                float2 v;
                v.x = relu(acc[2 * a][r]);
                v.y = relu(acc[2 * a + 1][r]);
                orow[16 * a + ln] = v;
            }
        }

        if (!more) break;
        s = sn;
    }
}

// ---------------- launch ----------------

extern "C" void kernel_launch(void* const* d_in, const int* in_sizes, int n_in,
                              void* d_out, int out_size, void* d_ws, size_t ws_size,
                              hipStream_t stream) {
    const float* atom = (const float*)d_in[0];   // [50000][133]
    const float* bond = (const float*)d_in[1];   // [800000][14]
    const float* Wi   = (const float*)d_in[2];   // [128][147]
    const float* Wh   = (const float*)d_in[3];   // [128][128]
    const float* Wo   = (const float*)d_in[4];   // [128][261]
    const int*   src  = (const int*)d_in[5]; (void)src;
    const int*   dst  = (const int*)d_in[6];
    const int*   rev  = (const int*)d_in[7];
    float* out = (float*)d_out;

    char* ws = (char*)d_ws;
    size_t off = 0;
    auto take = [&](size_t bytes) { char* p = ws + off; off = (off + bytes + 255) & ~(size_t)255; return p; };
    u32* hbuf   = (u32*)take((size_t)NE * 64 * 4);     // 204.8 MB
    u32* tmp    = (u32*)take((size_t)NN * 64 * 4);     // 12.8 MB
    u32* atomBf = (u32*)take((size_t)NN * ATU * 4);    // 13.6 MB
    int* fidx   = (int*)take((size_t)NE * 4);
    int* sidx   = (int*)take((size_t)NE * 4);
    int* posOf  = (int*)take((size_t)NE * 4);
    int* pidx   = (int*)take((size_t)NE * 4);
    int* cnt    = (int*)take((size_t)NN * 4);
    int* lexc   = (int*)take((size_t)NN * 4);
    int* rowptr = (int*)take((size_t)(NN + 1) * 4);
    int* cursor = (int*)take((size_t)NN * 4);
    int* chunkSum = (int*)take(256 * 4);
    int* chunkOff = (int*)take(256 * 4);
    u32* WiP = (u32*)take(128 * KPU1 * 4);
    u32* WhP = (u32*)take(128 * WHU * 4);
    u32* WoP = (u32*)take(128 * KPU3 * 4);
    // total ~245 MB (round-11 proven footprint)

    cvt_atom<<<2048, 256, 0, stream>>>(atom, atomBf);
    cvt_w<<<48, 256, 0, stream>>>(Wi, WiP, 147, KPU1, 133, 136, 14);
    cvt_w<<<32, 256, 0, stream>>>(Wh, WhP, 128, WHU, 128, 1 << 20, 0);
    cvt_w<<<80, 256, 0, stream>>>(Wo, WoP, 261, KPU3, 133, 136, 128);

    hipMemsetAsync(cnt, 0, (size_t)NN * 4, stream);
    hist<<<1024, 256, 0, stream>>>(dst, cnt);
    scan1<<<NCH, 256, 0, stream>>>(cnt, lexc, chunkSum);
    scan2<<<1, 256, 0, stream>>>(chunkSum, chunkOff);
    scan3<<<NCH, 256, 0, stream>>>(lexc, chunkOff, rowptr, cursor);
    scatter<<<1024, 256, 0, stream>>>(dst, rev, cursor, fidx, sidx, posOf);
    pidx_build<<<1024, 256, 0, stream>>>(fidx, posOf, pidx);

    k_init<<<768, 256, 0, stream>>>(atomBf, bond, fidx, sidx, pidx, WiP, hbuf);   // e-layout
    segsum_t<false><<<2048, 256, 0, stream>>>(rowptr, nullptr, hbuf, tmp);        // sequential
    k_msg_t<false><<<1024, 256, 0, stream>>>(sidx, pidx, WhP, tmp, hbuf);         // all-stream -> f-layout
    segsum_t<true><<<2048, 256, 0, stream>>>(rowptr, pidx, hbuf, tmp);            // gather
    k_msg_t<true><<<1024, 256, 0, stream>>>(sidx, pidx, WhP, tmp, hbuf);          // random rows -> e-layout
    segsum_t<false><<<2048, 256, 0, stream>>>(rowptr, nullptr, hbuf, tmp);        // sequential
    k_out_p<<<512, 256, 0, stream>>>(atomBf, WoP, tmp, out);
}